// Round 4
// baseline (774.609 us; speedup 1.0000x reference)
//
#include <hip/hip_runtime.h>

#define IN_DIM 128
#define HID 64
#define SHIFT 7                 // 128 nodes per bucket
#define BNODES 128
#define NBMAX 1024              // LDS arrays sized for NB <= 1024 (NB=782 @ N=100k)
#define CH 8192                 // edges per block in bucket count/place

// ---------------- Kernel 1: h1 = x @ W1 + b1   [N,128]@[128,64] ----------------
// 64x64 tile per block, 4x4 micro-tile per thread, W1 in LDS, unroll-1 k-loop
// (R2 lesson: full unroll -> 256 VGPR + 900 MB spill traffic).
__global__ __launch_bounds__(256) void gemm1_kernel(
    const float* __restrict__ x, const float* __restrict__ W1,
    const float* __restrict__ b1, float* __restrict__ h1, int N) {
  __shared__ float Ws[IN_DIM][HID];
  for (int i = threadIdx.x; i < IN_DIM * HID / 4; i += 256)
    reinterpret_cast<float4*>(&Ws[0][0])[i] = reinterpret_cast<const float4*>(W1)[i];
  __syncthreads();

  const int tx = threadIdx.x & 15;
  const int ty = threadIdx.x >> 4;
  const int j0 = tx * 4;
  const int rbase = blockIdx.x * 64 + ty * 4;

  float acc[4][4];
#pragma unroll
  for (int i = 0; i < 4; ++i)
#pragma unroll
    for (int c = 0; c < 4; ++c) acc[i][c] = 0.f;

  const float4* xp[4];
#pragma unroll
  for (int i = 0; i < 4; ++i) {
    int r = rbase + i;
    if (r > N - 1) r = N - 1;
    xp[i] = reinterpret_cast<const float4*>(x + (long)r * IN_DIM);
  }

#pragma unroll 1
  for (int k4 = 0; k4 < IN_DIM / 4; ++k4) {
    float xs[4][4];
#pragma unroll
    for (int i = 0; i < 4; ++i)
      *reinterpret_cast<float4*>(xs[i]) = xp[i][k4];
#pragma unroll
    for (int kk = 0; kk < 4; ++kk) {
      float wv[4];
      *reinterpret_cast<float4*>(wv) =
          *reinterpret_cast<const float4*>(&Ws[k4 * 4 + kk][j0]);
#pragma unroll
      for (int i = 0; i < 4; ++i)
#pragma unroll
        for (int c = 0; c < 4; ++c)
          acc[i][c] += xs[i][kk] * wv[c];
    }
  }

  float bb[4];
  *reinterpret_cast<float4*>(bb) = *reinterpret_cast<const float4*>(&b1[j0]);
#pragma unroll
  for (int i = 0; i < 4; ++i) {
    int r = rbase + i;
    if (r < N) {
      float4 o = make_float4(acc[i][0] + bb[0], acc[i][1] + bb[1],
                             acc[i][2] + bb[2], acc[i][3] + bb[3]);
      *reinterpret_cast<float4*>(h1 + (long)r * HID + j0) = o;
    }
  }
}

// ------------- Bucket partition pass 1: per-block histogram + reservation -------------
__global__ __launch_bounds__(256) void bucket_count_kernel(
    const int* __restrict__ dst, int* __restrict__ bucket_size,
    int* __restrict__ blockRel, int NB, int E) {
  __shared__ int hist[NBMAX];
  for (int i = threadIdx.x; i < NB; i += 256) hist[i] = 0;
  __syncthreads();
  int base = blockIdx.x * CH;
  int end = min(base + CH, E);
  for (int k = base + threadIdx.x; k < end; k += 256)
    atomicAdd(&hist[dst[k] >> SHIFT], 1);
  __syncthreads();
  for (int i = threadIdx.x; i < NB; i += 256) {
    int c = hist[i];
    int r = c ? atomicAdd(&bucket_size[i], c) : 0;
    blockRel[(long)blockIdx.x * NB + i] = r;
  }
}

// ------------- Pass 2: exclusive scan of bucket sizes (single block) -------------
__global__ __launch_bounds__(1024) void bucket_scan_kernel(
    const int* __restrict__ bucket_size, int* __restrict__ bucket_offs, int NB) {
  __shared__ int tmp[1024];
  int tid = threadIdx.x;
  int v = (tid < NB) ? bucket_size[tid] : 0;
  tmp[tid] = v;
  __syncthreads();
  for (int off = 1; off < 1024; off <<= 1) {
    int t = (tid >= off) ? tmp[tid - off] : 0;
    __syncthreads();
    tmp[tid] += t;
    __syncthreads();
  }
  if (tid <= NB) bucket_offs[tid] = tmp[tid] - v;  // exclusive; offs[NB]=E
}

// ------------- Pass 3: place edges into bucket-partitioned array -------------
// Packed entry: x = src | (dst_local << 20), y = weight bits.
__global__ __launch_bounds__(256) void bucket_place_kernel(
    const int* __restrict__ src, const int* __restrict__ dst,
    const float* __restrict__ w, const int* __restrict__ bucket_offs,
    const int* __restrict__ blockRel, int2* __restrict__ bpart, int NB, int E) {
  __shared__ int cur[NBMAX];
  for (int i = threadIdx.x; i < NB; i += 256)
    cur[i] = bucket_offs[i] + blockRel[(long)blockIdx.x * NB + i];
  __syncthreads();
  int base = blockIdx.x * CH;
  int end = min(base + CH, E);
  for (int k = base + threadIdx.x; k < end; k += 256) {
    int d = dst[k];
    int b = d >> SHIFT;
    int pos = atomicAdd(&cur[b], 1);
    bpart[pos] = make_int2(src[k] | ((d & (BNODES - 1)) << 20), __float_as_int(w[k]));
  }
}

// ------------- Fused SpMM1 + ReLU + lin2, one block per bucket -------------
// LDS acc[128][65] (pad 65: reduce-phase bank = (node+j)%32 -> conflict-free;
// edge-phase bank = (dl+lane)%32 -> 2 lanes/bank = free).
__global__ __launch_bounds__(256) void spmm1_bucket_kernel(
    const int2* __restrict__ bpart, const int* __restrict__ bucket_offs,
    const float* __restrict__ h1, const float* __restrict__ W2,
    const float* __restrict__ b2, float* __restrict__ h3, int N) {
  __shared__ float acc[BNODES][HID + 1];
  __shared__ float W2s[HID];
  const int t = threadIdx.x;
  for (int i = t; i < BNODES * (HID + 1); i += 256) (&acc[0][0])[i] = 0.f;
  if (t < HID) W2s[t] = W2[t];
  __syncthreads();

  const int b = blockIdx.x;
  const int beg = bucket_offs[b], end = bucket_offs[b + 1];
  const int wid = t >> 6, lane = t & 63;

  int k = beg + wid;
  for (; k + 4 < end; k += 8) {
    int2 e0 = bpart[k];
    int2 e1 = bpart[k + 4];
    float v0 = h1[(long)(e0.x & 0x1FFFF) * HID + lane];
    float v1 = h1[(long)(e1.x & 0x1FFFF) * HID + lane];
    atomicAdd(&acc[e0.x >> 20][lane], __int_as_float(e0.y) * v0);
    atomicAdd(&acc[e1.x >> 20][lane], __int_as_float(e1.y) * v1);
  }
  if (k < end) {
    int2 e = bpart[k];
    float v = h1[(long)(e.x & 0x1FFFF) * HID + lane];
    atomicAdd(&acc[e.x >> 20][lane], __int_as_float(e.y) * v);
  }
  __syncthreads();

  // 2 threads per node, 32 dims each: relu * W2, pairwise combine via shfl.
  const int n = t >> 1, hf = t & 1;
  const int node = (b << SHIFT) + n;
  float s = 0.f;
#pragma unroll
  for (int j0 = 0; j0 < 32; ++j0) {
    int j = hf * 32 + j0;
    s += fmaxf(acc[n][j], 0.f) * W2s[j];
  }
  s += __shfl_xor(s, 1, 64);
  if (hf == 0 && node < N) h3[node] = s + b2[0];
}

// ------------- SpMM2, one block per bucket, scalar LDS accumulator -------------
__global__ __launch_bounds__(256) void spmm2_bucket_kernel(
    const int2* __restrict__ bpart, const int* __restrict__ bucket_offs,
    const float* __restrict__ h3, float* __restrict__ out, int N) {
  __shared__ float accS[BNODES];
  const int t = threadIdx.x;
  if (t < BNODES) accS[t] = 0.f;
  __syncthreads();
  const int b = blockIdx.x;
  const int beg = bucket_offs[b], end = bucket_offs[b + 1];
  for (int k = beg + t; k < end; k += 256) {
    int2 e = bpart[k];
    atomicAdd(&accS[e.x >> 20], __int_as_float(e.y) * h3[e.x & 0x1FFFF]);
  }
  __syncthreads();
  const int node = (b << SHIFT) + t;
  if (t < BNODES && node < N) out[node] = accS[t];
}

extern "C" void kernel_launch(void* const* d_in, const int* in_sizes, int n_in,
                              void* d_out, int out_size, void* d_ws, size_t ws_size,
                              hipStream_t stream) {
  const float* x    = (const float*)d_in[0];
  const int*   esrc = (const int*)d_in[1];
  const int*   edst = (const int*)d_in[2];
  const float* ew   = (const float*)d_in[3];
  const float* W1   = (const float*)d_in[4];
  const float* b1   = (const float*)d_in[5];
  const float* W2   = (const float*)d_in[6];
  const float* b2   = (const float*)d_in[7];
  float* out = (float*)d_out;

  const int N = in_sizes[0] / IN_DIM;
  const int E = in_sizes[1];
  const int NB = (N + BNODES - 1) >> SHIFT;         // 782 @ N=100k (<= NBMAX)
  const int PBLK = (E + CH - 1) / CH;               // 196 @ E=1.6M

  // Workspace layout, 16B-aligned chunks.
  char* p = (char*)d_ws;
  auto alloc = [&](size_t bytes) {
    char* r = p;
    p += (bytes + 15) & ~(size_t)15;
    return r;
  };
  float* h1          = (float*)alloc((size_t)N * HID * sizeof(float));
  float* h3          = (float*)alloc((size_t)N * sizeof(float));
  int*   bucket_size = (int*)alloc((size_t)NB * sizeof(int));
  int*   bucket_offs = (int*)alloc((size_t)(NB + 1) * sizeof(int));
  int*   blockRel    = (int*)alloc((size_t)PBLK * NB * sizeof(int));
  int2*  bpart       = (int2*)alloc((size_t)E * sizeof(int2));

  hipMemsetAsync(bucket_size, 0, (size_t)NB * sizeof(int), stream);

  gemm1_kernel<<<(N + 63) / 64, 256, 0, stream>>>(x, W1, b1, h1, N);

  bucket_count_kernel<<<PBLK, 256, 0, stream>>>(edst, bucket_size, blockRel, NB, E);
  bucket_scan_kernel<<<1, 1024, 0, stream>>>(bucket_size, bucket_offs, NB);
  bucket_place_kernel<<<PBLK, 256, 0, stream>>>(esrc, edst, ew, bucket_offs,
                                                blockRel, bpart, NB, E);

  spmm1_bucket_kernel<<<NB, 256, 0, stream>>>(bpart, bucket_offs, h1, W2, b2, h3, N);
  spmm2_bucket_kernel<<<NB, 256, 0, stream>>>(bpart, bucket_offs, h3, out, N);
}

// Round 5
// 198.588 us; speedup vs baseline: 3.9006x; 3.9006x over previous
//
#include <hip/hip_runtime.h>

#define IN_DIM 128
#define HID 64
#define SHIFT 7                 // 128 nodes per bucket
#define BNODES 128
#define NBMAX 1024              // LDS arrays sized for NB <= 1024 (NB=782 @ N=100k)
#define CH 8192                 // edges per block in bucket count/place
#define SRCMASK 0xFFFFF         // src packed in low 20 bits (N <= 1M)

// ---------------- Kernel 1: h1 = x @ W1 + b1   [N,128]@[128,64] ----------------
// 64x64 tile per block, 4x4 micro-tile per thread, W1 in LDS, unroll-1 k-loop
// (R2 lesson: full unroll -> 256 VGPR + 900 MB spill traffic).
__global__ __launch_bounds__(256) void gemm1_kernel(
    const float* __restrict__ x, const float* __restrict__ W1,
    const float* __restrict__ b1, float* __restrict__ h1, int N) {
  __shared__ float Ws[IN_DIM][HID];
  for (int i = threadIdx.x; i < IN_DIM * HID / 4; i += 256)
    reinterpret_cast<float4*>(&Ws[0][0])[i] = reinterpret_cast<const float4*>(W1)[i];
  __syncthreads();

  const int tx = threadIdx.x & 15;
  const int ty = threadIdx.x >> 4;
  const int j0 = tx * 4;
  const int rbase = blockIdx.x * 64 + ty * 4;

  float acc[4][4];
#pragma unroll
  for (int i = 0; i < 4; ++i)
#pragma unroll
    for (int c = 0; c < 4; ++c) acc[i][c] = 0.f;

  const float4* xp[4];
#pragma unroll
  for (int i = 0; i < 4; ++i) {
    int r = rbase + i;
    if (r > N - 1) r = N - 1;
    xp[i] = reinterpret_cast<const float4*>(x + (long)r * IN_DIM);
  }

#pragma unroll 1
  for (int k4 = 0; k4 < IN_DIM / 4; ++k4) {
    float xs[4][4];
#pragma unroll
    for (int i = 0; i < 4; ++i)
      *reinterpret_cast<float4*>(xs[i]) = xp[i][k4];
#pragma unroll
    for (int kk = 0; kk < 4; ++kk) {
      float wv[4];
      *reinterpret_cast<float4*>(wv) =
          *reinterpret_cast<const float4*>(&Ws[k4 * 4 + kk][j0]);
#pragma unroll
      for (int i = 0; i < 4; ++i)
#pragma unroll
        for (int c = 0; c < 4; ++c)
          acc[i][c] += xs[i][kk] * wv[c];
    }
  }

  float bb[4];
  *reinterpret_cast<float4*>(bb) = *reinterpret_cast<const float4*>(&b1[j0]);
#pragma unroll
  for (int i = 0; i < 4; ++i) {
    int r = rbase + i;
    if (r < N) {
      float4 o = make_float4(acc[i][0] + bb[0], acc[i][1] + bb[1],
                             acc[i][2] + bb[2], acc[i][3] + bb[3]);
      *reinterpret_cast<float4*>(h1 + (long)r * HID + j0) = o;
    }
  }
}

// ------------- Bucket partition pass 1: per-block histogram + reservation -------------
__global__ __launch_bounds__(256) void bucket_count_kernel(
    const int* __restrict__ dst, int* __restrict__ bucket_size,
    int* __restrict__ blockRel, int NB, int E) {
  __shared__ int hist[NBMAX];
  for (int i = threadIdx.x; i < NB; i += 256) hist[i] = 0;
  __syncthreads();
  int base = blockIdx.x * CH;
  int end = min(base + CH, E);
  for (int k = base + threadIdx.x; k < end; k += 256)
    atomicAdd(&hist[dst[k] >> SHIFT], 1);
  __syncthreads();
  for (int i = threadIdx.x; i < NB; i += 256) {
    int c = hist[i];
    int r = c ? atomicAdd(&bucket_size[i], c) : 0;
    blockRel[(long)blockIdx.x * NB + i] = r;
  }
}

// ------------- Pass 2: exclusive scan of bucket sizes (single block) -------------
__global__ __launch_bounds__(1024) void bucket_scan_kernel(
    const int* __restrict__ bucket_size, int* __restrict__ bucket_offs, int NB) {
  __shared__ int tmp[1024];
  int tid = threadIdx.x;
  int v = (tid < NB) ? bucket_size[tid] : 0;
  tmp[tid] = v;
  __syncthreads();
  for (int off = 1; off < 1024; off <<= 1) {
    int t = (tid >= off) ? tmp[tid - off] : 0;
    __syncthreads();
    tmp[tid] += t;
    __syncthreads();
  }
  if (tid <= NB) bucket_offs[tid] = tmp[tid] - v;  // exclusive; offs[NB]=E
}

// ------------- Pass 3: place edges into bucket-partitioned array -------------
// Packed entry: x = src | (dst_local << 20), y = weight bits.
// Writes per (block,bucket) are contiguous chunks -> low write amplification.
__global__ __launch_bounds__(256) void bucket_place_kernel(
    const int* __restrict__ src, const int* __restrict__ dst,
    const float* __restrict__ w, const int* __restrict__ bucket_offs,
    const int* __restrict__ blockRel, int2* __restrict__ bpart, int NB, int E) {
  __shared__ int cur[NBMAX];
  for (int i = threadIdx.x; i < NB; i += 256)
    cur[i] = bucket_offs[i] + blockRel[(long)blockIdx.x * NB + i];
  __syncthreads();
  int base = blockIdx.x * CH;
  int end = min(base + CH, E);
  for (int k = base + threadIdx.x; k < end; k += 256) {
    int d = dst[k];
    int b = d >> SHIFT;
    int pos = atomicAdd(&cur[b], 1);
    bpart[pos] = make_int2((src[k] & SRCMASK) | ((d & (BNODES - 1)) << 20),
                           __float_as_int(w[k]));
  }
}

// ------------- Pass 4: per-bucket CSR finalize -------------
// One block per bucket. Local 128-node histogram + scan; place edges into the
// bucket's CONTIGUOUS csr segment (fully-dirty 64B lines -> no write amp).
__global__ __launch_bounds__(256) void csr_place_kernel(
    const int2* __restrict__ bpart, const int* __restrict__ bucket_offs,
    int2* __restrict__ csr, int* __restrict__ noffs, int N, int NB, int E) {
  __shared__ int cnt[BNODES];
  __shared__ int cur[BNODES];
  __shared__ int wtot[2];
  const int t = threadIdx.x;
  const int b = blockIdx.x;
  const int beg = bucket_offs[b], end = bucket_offs[b + 1];

  for (int i = t; i < BNODES; i += 256) cnt[i] = 0;
  __syncthreads();

  for (int k = beg + t; k < end; k += 256)
    atomicAdd(&cnt[bpart[k].x >> 20], 1);
  __syncthreads();

  // exclusive scan of cnt[0..127] using waves 0,1 (no divergent barriers)
  int v = 0, s = 0;
  if (t < BNODES) {
    v = cnt[t];
    s = v;
#pragma unroll
    for (int d = 1; d < 64; d <<= 1) {
      int u = __shfl_up(s, d, 64);
      if ((t & 63) >= d) s += u;
    }
    if ((t & 63) == 63) wtot[t >> 6] = s;
  }
  __syncthreads();
  if (t < BNODES) {
    int g = beg + ((t >= 64) ? wtot[0] : 0) + s - v;  // global exclusive offset
    cur[t] = g;
    int node = (b << SHIFT) + t;
    if (node < N) noffs[node] = g;
  }
  if (b == NB - 1 && t == 0) noffs[N] = E;
  __syncthreads();

  for (int k = beg + t; k < end; k += 256) {
    int2 e = bpart[k];
    int dl = e.x >> 20;
    int pos = atomicAdd(&cur[dl], 1);
    csr[pos] = make_int2(e.x & SRCMASK, e.y);
  }
}

// ---------------- Fused: h3[n] = relu(sum_e w*h1[src_e]) . W2 + b2 ----------------
// One 64-lane wave per node; lane = hidden dim. Unroll-4 for in-flight gathers.
__global__ __launch_bounds__(256) void spmm1_fused_kernel(
    const int* __restrict__ noffs, const int2* __restrict__ csr,
    const float* __restrict__ h1, const float* __restrict__ W2,
    const float* __restrict__ b2, float* __restrict__ h3, int N) {
  int wave = (blockIdx.x * 256 + threadIdx.x) >> 6;
  int lane = threadIdx.x & 63;
  if (wave >= N) return;
  int beg = noffs[wave], end = noffs[wave + 1];
  float acc = 0.f;
  int k = beg;
  for (; k + 3 < end; k += 4) {
    int2 e0 = csr[k], e1 = csr[k + 1], e2 = csr[k + 2], e3 = csr[k + 3];
    float v0 = h1[(long)(e0.x) * HID + lane];
    float v1 = h1[(long)(e1.x) * HID + lane];
    float v2 = h1[(long)(e2.x) * HID + lane];
    float v3 = h1[(long)(e3.x) * HID + lane];
    acc += __int_as_float(e0.y) * v0;
    acc += __int_as_float(e1.y) * v1;
    acc += __int_as_float(e2.y) * v2;
    acc += __int_as_float(e3.y) * v3;
  }
  for (; k < end; ++k) {
    int2 e = csr[k];
    acc += __int_as_float(e.y) * h1[(long)(e.x) * HID + lane];
  }
  float r = fmaxf(acc, 0.f) * W2[lane];
#pragma unroll
  for (int off = 32; off > 0; off >>= 1) r += __shfl_down(r, off, 64);
  if (lane == 0) h3[wave] = r + b2[0];
}

// ---------------- Gather spmm2: out[n] = sum_e w*h3[src_e] ----------------
__global__ __launch_bounds__(256) void spmm2_gather_kernel(
    const int* __restrict__ noffs, const int2* __restrict__ csr,
    const float* __restrict__ h3, float* __restrict__ out, int N) {
  int n = blockIdx.x * 256 + threadIdx.x;
  if (n >= N) return;
  int beg = noffs[n], end = noffs[n + 1];
  float acc = 0.f;
  for (int k = beg; k < end; ++k) {
    int2 e = csr[k];
    acc += __int_as_float(e.y) * h3[e.x];
  }
  out[n] = acc;
}

extern "C" void kernel_launch(void* const* d_in, const int* in_sizes, int n_in,
                              void* d_out, int out_size, void* d_ws, size_t ws_size,
                              hipStream_t stream) {
  const float* x    = (const float*)d_in[0];
  const int*   esrc = (const int*)d_in[1];
  const int*   edst = (const int*)d_in[2];
  const float* ew   = (const float*)d_in[3];
  const float* W1   = (const float*)d_in[4];
  const float* b1   = (const float*)d_in[5];
  const float* W2   = (const float*)d_in[6];
  const float* b2   = (const float*)d_in[7];
  float* out = (float*)d_out;

  const int N = in_sizes[0] / IN_DIM;
  const int E = in_sizes[1];
  const int NB = (N + BNODES - 1) >> SHIFT;         // 782 @ N=100k
  const int PBLK = (E + CH - 1) / CH;               // 196 @ E=1.6M

  char* p = (char*)d_ws;
  auto alloc = [&](size_t bytes) {
    char* r = p;
    p += (bytes + 15) & ~(size_t)15;
    return r;
  };
  float* h1          = (float*)alloc((size_t)N * HID * sizeof(float));
  float* h3          = (float*)alloc((size_t)N * sizeof(float));
  int*   bucket_size = (int*)alloc((size_t)NB * sizeof(int));
  int*   bucket_offs = (int*)alloc((size_t)(NB + 1) * sizeof(int));
  int*   noffs       = (int*)alloc((size_t)(N + 1) * sizeof(int));
  int*   blockRel    = (int*)alloc((size_t)PBLK * NB * sizeof(int));
  int2*  bpart       = (int2*)alloc((size_t)E * sizeof(int2));
  int2*  csr         = (int2*)alloc((size_t)E * sizeof(int2));

  hipMemsetAsync(bucket_size, 0, (size_t)NB * sizeof(int), stream);

  gemm1_kernel<<<(N + 63) / 64, 256, 0, stream>>>(x, W1, b1, h1, N);

  bucket_count_kernel<<<PBLK, 256, 0, stream>>>(edst, bucket_size, blockRel, NB, E);
  bucket_scan_kernel<<<1, 1024, 0, stream>>>(bucket_size, bucket_offs, NB);
  bucket_place_kernel<<<PBLK, 256, 0, stream>>>(esrc, edst, ew, bucket_offs,
                                                blockRel, bpart, NB, E);
  csr_place_kernel<<<NB, 256, 0, stream>>>(bpart, bucket_offs, csr, noffs, N, NB, E);

  spmm1_fused_kernel<<<(unsigned)(((long)N * 64 + 255) / 256), 256, 0, stream>>>(
      noffs, csr, h1, W2, b2, h3, N);

  spmm2_gather_kernel<<<(N + 255) / 256, 256, 0, stream>>>(noffs, csr, h3, out, N);
}

// Round 6
// 192.857 us; speedup vs baseline: 4.0165x; 1.0297x over previous
//
#include <hip/hip_runtime.h>

#define IN_DIM 128
#define HID 64
#define SHIFT 8                 // 256 nodes per bucket
#define BNODES 256
#define NBMAX 1024              // LDS hist sized for NB <= 1024 (NB=391 @ N=100k)
#define CH 8192                 // edges per block in bucket count/place
#define SRCMASK 0xFFFFF         // src packed in low 20 bits (N <= 1M)
#define LDSCAP 6144             // csr_place LDS edge-staging capacity (48 KB)

// bf16 round-to-nearest-even
__device__ inline unsigned short f2bf(float f) {
  unsigned u = __float_as_uint(f);
  u += 0x7FFF + ((u >> 16) & 1);
  return (unsigned short)(u >> 16);
}
__device__ inline float bf2f(unsigned short b) {
  return __uint_as_float(((unsigned)b) << 16);
}

// ---------------- Kernel 1: h1 = bf16(x @ W1 + b1)   [N,128]@[128,64] ----------------
// 64x64 tile per block, 4x4 micro-tile per thread, W1 in LDS, unroll-1 k-loop
// (R2 lesson: full unroll -> 256 VGPR + 900 MB spill traffic).
__global__ __launch_bounds__(256) void gemm1_kernel(
    const float* __restrict__ x, const float* __restrict__ W1,
    const float* __restrict__ b1, unsigned short* __restrict__ h1, int N) {
  __shared__ float Ws[IN_DIM][HID];
  for (int i = threadIdx.x; i < IN_DIM * HID / 4; i += 256)
    reinterpret_cast<float4*>(&Ws[0][0])[i] = reinterpret_cast<const float4*>(W1)[i];
  __syncthreads();

  const int tx = threadIdx.x & 15;
  const int ty = threadIdx.x >> 4;
  const int j0 = tx * 4;
  const int rbase = blockIdx.x * 64 + ty * 4;

  float acc[4][4];
#pragma unroll
  for (int i = 0; i < 4; ++i)
#pragma unroll
    for (int c = 0; c < 4; ++c) acc[i][c] = 0.f;

  const float4* xp[4];
#pragma unroll
  for (int i = 0; i < 4; ++i) {
    int r = rbase + i;
    if (r > N - 1) r = N - 1;
    xp[i] = reinterpret_cast<const float4*>(x + (long)r * IN_DIM);
  }

#pragma unroll 1
  for (int k4 = 0; k4 < IN_DIM / 4; ++k4) {
    float xs[4][4];
#pragma unroll
    for (int i = 0; i < 4; ++i)
      *reinterpret_cast<float4*>(xs[i]) = xp[i][k4];
#pragma unroll
    for (int kk = 0; kk < 4; ++kk) {
      float wv[4];
      *reinterpret_cast<float4*>(wv) =
          *reinterpret_cast<const float4*>(&Ws[k4 * 4 + kk][j0]);
#pragma unroll
      for (int i = 0; i < 4; ++i)
#pragma unroll
        for (int c = 0; c < 4; ++c)
          acc[i][c] += xs[i][kk] * wv[c];
    }
  }

  float bb[4];
  *reinterpret_cast<float4*>(bb) = *reinterpret_cast<const float4*>(&b1[j0]);
#pragma unroll
  for (int i = 0; i < 4; ++i) {
    int r = rbase + i;
    if (r < N) {
      ushort4 o;
      o.x = f2bf(acc[i][0] + bb[0]);
      o.y = f2bf(acc[i][1] + bb[1]);
      o.z = f2bf(acc[i][2] + bb[2]);
      o.w = f2bf(acc[i][3] + bb[3]);
      *reinterpret_cast<ushort4*>(h1 + (long)r * HID + j0) = o;
    }
  }
}

// ------------- Bucket partition pass 1: per-block histogram + reservation -------------
__global__ __launch_bounds__(256) void bucket_count_kernel(
    const int* __restrict__ dst, int* __restrict__ bucket_size,
    int* __restrict__ blockRel, int NB, int E) {
  __shared__ int hist[NBMAX];
  for (int i = threadIdx.x; i < NB; i += 256) hist[i] = 0;
  __syncthreads();
  int base = blockIdx.x * CH;
  int end = min(base + CH, E);
  for (int k = base + threadIdx.x; k < end; k += 256)
    atomicAdd(&hist[dst[k] >> SHIFT], 1);
  __syncthreads();
  for (int i = threadIdx.x; i < NB; i += 256) {
    int c = hist[i];
    int r = c ? atomicAdd(&bucket_size[i], c) : 0;
    blockRel[(long)blockIdx.x * NB + i] = r;
  }
}

// ------------- Pass 2: exclusive scan of bucket sizes (single block) -------------
__global__ __launch_bounds__(1024) void bucket_scan_kernel(
    const int* __restrict__ bucket_size, int* __restrict__ bucket_offs, int NB) {
  __shared__ int tmp[1024];
  int tid = threadIdx.x;
  int v = (tid < NB) ? bucket_size[tid] : 0;
  tmp[tid] = v;
  __syncthreads();
  for (int off = 1; off < 1024; off <<= 1) {
    int t = (tid >= off) ? tmp[tid - off] : 0;
    __syncthreads();
    tmp[tid] += t;
    __syncthreads();
  }
  if (tid <= NB) bucket_offs[tid] = tmp[tid] - v;  // exclusive; offs[NB]=E
}

// ------------- Pass 3: place edges into bucket-partitioned array -------------
// Packed entry: x = src | (dst_local << 20), y = weight bits.
__global__ __launch_bounds__(256) void bucket_place_kernel(
    const int* __restrict__ src, const int* __restrict__ dst,
    const float* __restrict__ w, const int* __restrict__ bucket_offs,
    const int* __restrict__ blockRel, int2* __restrict__ bpart, int NB, int E) {
  __shared__ int cur[NBMAX];
  for (int i = threadIdx.x; i < NB; i += 256)
    cur[i] = bucket_offs[i] + blockRel[(long)blockIdx.x * NB + i];
  __syncthreads();
  int base = blockIdx.x * CH;
  int end = min(base + CH, E);
  for (int k = base + threadIdx.x; k < end; k += 256) {
    int d = dst[k];
    int b = d >> SHIFT;
    int pos = atomicAdd(&cur[b], 1);
    bpart[pos] = make_int2((src[k] & SRCMASK) | ((d & (BNODES - 1)) << 20),
                           __float_as_int(w[k]));
  }
}

// ------------- Pass 4: per-bucket CSR finalize (LDS-staged) -------------
// One block per bucket (256 nodes). Stage segment in LDS (one coalesced global
// read), 256-node histogram + shfl scan, scatter into the bucket's CONTIGUOUS
// csr segment. Fallback to global reads if a bucket exceeds LDSCAP (keeps
// correctness independent of dst distribution).
__global__ __launch_bounds__(256) void csr_place_kernel(
    const int2* __restrict__ bpart, const int* __restrict__ bucket_offs,
    int2* __restrict__ csr, int* __restrict__ noffs, int N, int NB, int E) {
  __shared__ int cnt[BNODES];
  __shared__ int cur[BNODES];
  __shared__ int wtot[4];
  __shared__ int2 ebuf[LDSCAP];
  const int t = threadIdx.x;
  const int b = blockIdx.x;
  const int beg = bucket_offs[b], end = bucket_offs[b + 1];
  const int len = end - beg;
  const bool useLds = (len <= LDSCAP);

  cnt[t] = 0;
  __syncthreads();

  if (useLds) {
    for (int k = t; k < len; k += 256) {
      int2 e = bpart[beg + k];
      ebuf[k] = e;
      atomicAdd(&cnt[e.x >> 20], 1);
    }
  } else {
    for (int k = beg + t; k < end; k += 256)
      atomicAdd(&cnt[bpart[k].x >> 20], 1);
  }
  __syncthreads();

  // exclusive scan of cnt[0..255]: per-wave shfl scan + wave-total combine
  int v = cnt[t], s = v;
#pragma unroll
  for (int d = 1; d < 64; d <<= 1) {
    int u = __shfl_up(s, d, 64);
    if ((t & 63) >= d) s += u;
  }
  if ((t & 63) == 63) wtot[t >> 6] = s;
  __syncthreads();
  int base = 0;
  const int wv_ = t >> 6;
  if (wv_ > 0) base += wtot[0];
  if (wv_ > 1) base += wtot[1];
  if (wv_ > 2) base += wtot[2];
  const int g = beg + base + s - v;  // global exclusive offset for node t
  cur[t] = g;
  const int node = (b << SHIFT) + t;
  if (node < N) noffs[node] = g;
  if (b == NB - 1 && t == 0) noffs[N] = E;
  __syncthreads();

  if (useLds) {
    for (int k = t; k < len; k += 256) {
      int2 e = ebuf[k];
      int pos = atomicAdd(&cur[e.x >> 20], 1);
      csr[pos] = make_int2(e.x & SRCMASK, e.y);
    }
  } else {
    for (int k = beg + t; k < end; k += 256) {
      int2 e = bpart[k];
      int pos = atomicAdd(&cur[e.x >> 20], 1);
      csr[pos] = make_int2(e.x & SRCMASK, e.y);
    }
  }
}

// ---------------- Fused: h3[n] = relu(sum_e w*h1[src_e]) . W2 + b2 ----------------
// One 64-lane wave per node; lane = hidden dim; bf16 h1 gather (128 B/edge).
__global__ __launch_bounds__(256) void spmm1_fused_kernel(
    const int* __restrict__ noffs, const int2* __restrict__ csr,
    const unsigned short* __restrict__ h1, const float* __restrict__ W2,
    const float* __restrict__ b2, float* __restrict__ h3, int N) {
  int wave = (blockIdx.x * 256 + threadIdx.x) >> 6;
  int lane = threadIdx.x & 63;
  if (wave >= N) return;
  int beg = noffs[wave], end = noffs[wave + 1];
  float acc = 0.f;
  int k = beg;
  for (; k + 3 < end; k += 4) {
    int2 e0 = csr[k], e1 = csr[k + 1], e2 = csr[k + 2], e3 = csr[k + 3];
    float v0 = bf2f(h1[(long)e0.x * HID + lane]);
    float v1 = bf2f(h1[(long)e1.x * HID + lane]);
    float v2 = bf2f(h1[(long)e2.x * HID + lane]);
    float v3 = bf2f(h1[(long)e3.x * HID + lane]);
    acc += __int_as_float(e0.y) * v0;
    acc += __int_as_float(e1.y) * v1;
    acc += __int_as_float(e2.y) * v2;
    acc += __int_as_float(e3.y) * v3;
  }
  for (; k < end; ++k) {
    int2 e = csr[k];
    acc += __int_as_float(e.y) * bf2f(h1[(long)e.x * HID + lane]);
  }
  float r = fmaxf(acc, 0.f) * W2[lane];
#pragma unroll
  for (int off = 32; off > 0; off >>= 1) r += __shfl_down(r, off, 64);
  if (lane == 0) h3[wave] = r + b2[0];
}

// ---------------- Gather spmm2: out[n] = sum_e w*h3[src_e] ----------------
__global__ __launch_bounds__(256) void spmm2_gather_kernel(
    const int* __restrict__ noffs, const int2* __restrict__ csr,
    const float* __restrict__ h3, float* __restrict__ out, int N) {
  int n = blockIdx.x * 256 + threadIdx.x;
  if (n >= N) return;
  int beg = noffs[n], end = noffs[n + 1];
  float acc = 0.f;
  for (int k = beg; k < end; ++k) {
    int2 e = csr[k];
    acc += __int_as_float(e.y) * h3[e.x];
  }
  out[n] = acc;
}

extern "C" void kernel_launch(void* const* d_in, const int* in_sizes, int n_in,
                              void* d_out, int out_size, void* d_ws, size_t ws_size,
                              hipStream_t stream) {
  const float* x    = (const float*)d_in[0];
  const int*   esrc = (const int*)d_in[1];
  const int*   edst = (const int*)d_in[2];
  const float* ew   = (const float*)d_in[3];
  const float* W1   = (const float*)d_in[4];
  const float* b1   = (const float*)d_in[5];
  const float* W2   = (const float*)d_in[6];
  const float* b2   = (const float*)d_in[7];
  float* out = (float*)d_out;

  const int N = in_sizes[0] / IN_DIM;
  const int E = in_sizes[1];
  const int NB = (N + BNODES - 1) >> SHIFT;         // 391 @ N=100k
  const int PBLK = (E + CH - 1) / CH;               // 196 @ E=1.6M

  char* p = (char*)d_ws;
  auto alloc = [&](size_t bytes) {
    char* r = p;
    p += (bytes + 15) & ~(size_t)15;
    return r;
  };
  unsigned short* h1 = (unsigned short*)alloc((size_t)N * HID * sizeof(unsigned short));
  float* h3          = (float*)alloc((size_t)N * sizeof(float));
  int*   bucket_size = (int*)alloc((size_t)NB * sizeof(int));
  int*   bucket_offs = (int*)alloc((size_t)(NB + 1) * sizeof(int));
  int*   noffs       = (int*)alloc((size_t)(N + 1) * sizeof(int));
  int*   blockRel    = (int*)alloc((size_t)PBLK * NB * sizeof(int));
  int2*  bpart       = (int2*)alloc((size_t)E * sizeof(int2));
  int2*  csr         = (int2*)alloc((size_t)E * sizeof(int2));

  hipMemsetAsync(bucket_size, 0, (size_t)NB * sizeof(int), stream);

  gemm1_kernel<<<(N + 63) / 64, 256, 0, stream>>>(x, W1, b1, h1, N);

  bucket_count_kernel<<<PBLK, 256, 0, stream>>>(edst, bucket_size, blockRel, NB, E);
  bucket_scan_kernel<<<1, 1024, 0, stream>>>(bucket_size, bucket_offs, NB);
  bucket_place_kernel<<<PBLK, 256, 0, stream>>>(esrc, edst, ew, bucket_offs,
                                                blockRel, bpart, NB, E);
  csr_place_kernel<<<NB, 256, 0, stream>>>(bpart, bucket_offs, csr, noffs, N, NB, E);

  spmm1_fused_kernel<<<(unsigned)(((long)N * 64 + 255) / 256), 256, 0, stream>>>(
      noffs, csr, h1, W2, b2, h3, N);

  spmm2_gather_kernel<<<(N + 255) / 256, 256, 0, stream>>>(noffs, csr, h3, out, N);
}

// Round 8
// 182.842 us; speedup vs baseline: 4.2365x; 1.0548x over previous
//
#include <hip/hip_runtime.h>

#define IN_DIM 128
#define HID 64
#define SHIFT 8                 // 256 nodes per bucket
#define BNODES 256
#define NBMAX 1024              // NB=391 @ N=100k
#define CH 8192                 // edges per block in bucket count/place
#define SRCMASK 0xFFFFF         // src packed in low 20 bits (N <= 1M)
#define LDSCAP 6144             // csr_place LDS edge-staging capacity (48 KB)

// bf16 round-to-nearest-even
__device__ inline unsigned short f2bf(float f) {
  unsigned u = __float_as_uint(f);
  u += 0x7FFF + ((u >> 16) & 1);
  return (unsigned short)(u >> 16);
}
__device__ inline float bf2f_lo(unsigned v) {   // low bf16 of a packed u32
  return __uint_as_float(v << 16);
}
__device__ inline float bf2f_hi(unsigned v) {   // high bf16 of a packed u32
  return __uint_as_float(v & 0xFFFF0000u);
}

// ---------------- Kernel 1: h1 = bf16(x @ W1 + b1)   [N,128]@[128,64] ----------------
// 64x64 tile per block, 4x4 micro-tile per thread, W1 in LDS, unroll-1 k-loop
// (R2 lesson: full unroll -> 256 VGPR + 900 MB spill traffic).
// R7 lesson: do NOT fuse bucket_count into this kernel — replay-only
// divergence appeared with the fusion; separate launches are stable.
__global__ __launch_bounds__(256) void gemm1_kernel(
    const float* __restrict__ x, const float* __restrict__ W1,
    const float* __restrict__ b1, unsigned short* __restrict__ h1, int N) {
  __shared__ float Ws[IN_DIM][HID];
  for (int i = threadIdx.x; i < IN_DIM * HID / 4; i += 256)
    reinterpret_cast<float4*>(&Ws[0][0])[i] = reinterpret_cast<const float4*>(W1)[i];
  __syncthreads();

  const int tx = threadIdx.x & 15;
  const int ty = threadIdx.x >> 4;
  const int j0 = tx * 4;
  const int rbase = blockIdx.x * 64 + ty * 4;

  float acc[4][4];
#pragma unroll
  for (int i = 0; i < 4; ++i)
#pragma unroll
    for (int c = 0; c < 4; ++c) acc[i][c] = 0.f;

  const float4* xp[4];
#pragma unroll
  for (int i = 0; i < 4; ++i) {
    int r = rbase + i;
    if (r > N - 1) r = N - 1;
    xp[i] = reinterpret_cast<const float4*>(x + (long)r * IN_DIM);
  }

#pragma unroll 1
  for (int k4 = 0; k4 < IN_DIM / 4; ++k4) {
    float xs[4][4];
#pragma unroll
    for (int i = 0; i < 4; ++i)
      *reinterpret_cast<float4*>(xs[i]) = xp[i][k4];
#pragma unroll
    for (int kk = 0; kk < 4; ++kk) {
      float wv[4];
      *reinterpret_cast<float4*>(wv) =
          *reinterpret_cast<const float4*>(&Ws[k4 * 4 + kk][j0]);
#pragma unroll
      for (int i = 0; i < 4; ++i)
#pragma unroll
        for (int c = 0; c < 4; ++c)
          acc[i][c] += xs[i][kk] * wv[c];
    }
  }

  float bb[4];
  *reinterpret_cast<float4*>(bb) = *reinterpret_cast<const float4*>(&b1[j0]);
#pragma unroll
  for (int i = 0; i < 4; ++i) {
    int r = rbase + i;
    if (r < N) {
      ushort4 o;
      o.x = f2bf(acc[i][0] + bb[0]);
      o.y = f2bf(acc[i][1] + bb[1]);
      o.z = f2bf(acc[i][2] + bb[2]);
      o.w = f2bf(acc[i][3] + bb[3]);
      *reinterpret_cast<ushort4*>(h1 + (long)r * HID + j0) = o;
    }
  }
}

// ------------- Bucket partition pass 1: per-block histogram + reservation -------------
__global__ __launch_bounds__(256) void bucket_count_kernel(
    const int* __restrict__ dst, int* __restrict__ bucket_size,
    int* __restrict__ blockRel, int NB, int E) {
  __shared__ int hist[NBMAX];
  for (int i = threadIdx.x; i < NB; i += 256) hist[i] = 0;
  __syncthreads();
  int base = blockIdx.x * CH;
  int end = min(base + CH, E);
  for (int k = base + threadIdx.x; k < end; k += 256)
    atomicAdd(&hist[dst[k] >> SHIFT], 1);
  __syncthreads();
  for (int i = threadIdx.x; i < NB; i += 256) {
    int c = hist[i];
    int r = c ? atomicAdd(&bucket_size[i], c) : 0;
    blockRel[(long)blockIdx.x * NB + i] = r;
  }
}

// ------------- Pass 2: exclusive scan of bucket sizes (single block) -------------
__global__ __launch_bounds__(1024) void bucket_scan_kernel(
    const int* __restrict__ bucket_size, int* __restrict__ bucket_offs, int NB) {
  __shared__ int tmp[1024];
  int tid = threadIdx.x;
  int v = (tid < NB) ? bucket_size[tid] : 0;
  tmp[tid] = v;
  __syncthreads();
  for (int off = 1; off < 1024; off <<= 1) {
    int t = (tid >= off) ? tmp[tid - off] : 0;
    __syncthreads();
    tmp[tid] += t;
    __syncthreads();
  }
  if (tid <= NB) bucket_offs[tid] = tmp[tid] - v;  // exclusive; offs[NB]=E
}

// ------------- Pass 3: place edges into bucket-partitioned array -------------
// Packed entry: x = src | (dst_local << 20), y = weight bits.
__global__ __launch_bounds__(256) void bucket_place_kernel(
    const int* __restrict__ src, const int* __restrict__ dst,
    const float* __restrict__ w, const int* __restrict__ bucket_offs,
    const int* __restrict__ blockRel, int2* __restrict__ bpart, int NB, int E) {
  __shared__ int cur[NBMAX];
  for (int i = threadIdx.x; i < NB; i += 256)
    cur[i] = bucket_offs[i] + blockRel[(long)blockIdx.x * NB + i];
  __syncthreads();
  int base = blockIdx.x * CH;
  int end = min(base + CH, E);
  for (int k = base + threadIdx.x; k < end; k += 256) {
    int d = dst[k];
    int b = d >> SHIFT;
    int pos = atomicAdd(&cur[b], 1);
    bpart[pos] = make_int2((src[k] & SRCMASK) | ((d & (BNODES - 1)) << 20),
                           __float_as_int(w[k]));
  }
}

// ------------- Pass 4: per-bucket CSR finalize (LDS-staged) -------------
__global__ __launch_bounds__(256) void csr_place_kernel(
    const int2* __restrict__ bpart, const int* __restrict__ bucket_offs,
    int2* __restrict__ csr, int* __restrict__ noffs, int N, int NB, int E) {
  __shared__ int cnt[BNODES];
  __shared__ int cur[BNODES];
  __shared__ int wtot[4];
  __shared__ int2 ebuf[LDSCAP];
  const int t = threadIdx.x;
  const int b = blockIdx.x;
  const int beg = bucket_offs[b], end = bucket_offs[b + 1];
  const int len = end - beg;
  const bool useLds = (len <= LDSCAP);

  cnt[t] = 0;
  __syncthreads();

  if (useLds) {
    for (int k = t; k < len; k += 256) {
      int2 e = bpart[beg + k];
      ebuf[k] = e;
      atomicAdd(&cnt[e.x >> 20], 1);
    }
  } else {
    for (int k = beg + t; k < end; k += 256)
      atomicAdd(&cnt[bpart[k].x >> 20], 1);
  }
  __syncthreads();

  // exclusive scan of cnt[0..255]: per-wave shfl scan + wave-total combine
  int v = cnt[t], s = v;
#pragma unroll
  for (int d = 1; d < 64; d <<= 1) {
    int u = __shfl_up(s, d, 64);
    if ((t & 63) >= d) s += u;
  }
  if ((t & 63) == 63) wtot[t >> 6] = s;
  __syncthreads();
  int base = 0;
  const int wv_ = t >> 6;
  if (wv_ > 0) base += wtot[0];
  if (wv_ > 1) base += wtot[1];
  if (wv_ > 2) base += wtot[2];
  const int g = beg + base + s - v;  // global exclusive offset for node t
  cur[t] = g;
  const int node = (b << SHIFT) + t;
  if (node < N) noffs[node] = g;
  if (b == NB - 1 && t == 0) noffs[N] = E;
  __syncthreads();

  if (useLds) {
    for (int k = t; k < len; k += 256) {
      int2 e = ebuf[k];
      int pos = atomicAdd(&cur[e.x >> 20], 1);
      csr[pos] = make_int2(e.x & SRCMASK, e.y);
    }
  } else {
    for (int k = beg + t; k < end; k += 256) {
      int2 e = bpart[k];
      int pos = atomicAdd(&cur[e.x >> 20], 1);
      csr[pos] = make_int2(e.x & SRCMASK, e.y);
    }
  }
}

// ---------------- Fused: h3[n] = relu(sum_e w*h1[src_e]) . W2 + b2 ----------------
// One 64-lane wave per node. Wave split into two 32-lane halves; each half
// handles one edge per iteration with ushort2 loads (2 dims / lane).
// Halves combined with a single shfl_xor(32) after the loop. Deterministic
// given (noffs, csr, h1): edge partition is order-independent.
__global__ __launch_bounds__(256) void spmm1_fused_kernel(
    const int* __restrict__ noffs, const int2* __restrict__ csr,
    const unsigned short* __restrict__ h1, const float* __restrict__ W2,
    const float* __restrict__ b2, float* __restrict__ h3, int N) {
  int wave = (blockIdx.x * 256 + threadIdx.x) >> 6;
  int lane = threadIdx.x & 63;
  if (wave >= N) return;
  int beg = noffs[wave], end = noffs[wave + 1];
  const int half = lane >> 5;
  const int l32 = lane & 31;

  float a0 = 0.f, a1 = 0.f;
  int k = beg + half;
  // 4 edges per wave-iteration (2 per half), unroll-2 for in-flight gathers
  for (; k + 2 < end; k += 4) {
    int2 eA = csr[k], eB = csr[k + 2];
    unsigned vA = *reinterpret_cast<const unsigned*>(h1 + (long)eA.x * HID + 2 * l32);
    unsigned vB = *reinterpret_cast<const unsigned*>(h1 + (long)eB.x * HID + 2 * l32);
    float wA = __int_as_float(eA.y), wB = __int_as_float(eB.y);
    a0 += wA * bf2f_lo(vA);
    a1 += wA * bf2f_hi(vA);
    a0 += wB * bf2f_lo(vB);
    a1 += wB * bf2f_hi(vB);
  }
  for (; k < end; k += 2) {
    int2 e = csr[k];
    unsigned v = *reinterpret_cast<const unsigned*>(h1 + (long)e.x * HID + 2 * l32);
    float w = __int_as_float(e.y);
    a0 += w * bf2f_lo(v);
    a1 += w * bf2f_hi(v);
  }

  // combine the two half-wave edge subsets
  a0 += __shfl_xor(a0, 32, 64);
  a1 += __shfl_xor(a1, 32, 64);

  float2 w2 = *reinterpret_cast<const float2*>(W2 + 2 * l32);
  float s = fmaxf(a0, 0.f) * w2.x + fmaxf(a1, 0.f) * w2.y;
#pragma unroll
  for (int off = 16; off > 0; off >>= 1) s += __shfl_xor(s, off, 64);
  if (lane == 0) h3[wave] = s + b2[0];
}

// ---------------- Gather spmm2: out[n] = sum_e w*h3[src_e] ----------------
__global__ __launch_bounds__(256) void spmm2_gather_kernel(
    const int* __restrict__ noffs, const int2* __restrict__ csr,
    const float* __restrict__ h3, float* __restrict__ out, int N) {
  int n = blockIdx.x * 256 + threadIdx.x;
  if (n >= N) return;
  int beg = noffs[n], end = noffs[n + 1];
  float acc = 0.f;
  for (int k = beg; k < end; ++k) {
    int2 e = csr[k];
    acc += __int_as_float(e.y) * h3[e.x];
  }
  out[n] = acc;
}

extern "C" void kernel_launch(void* const* d_in, const int* in_sizes, int n_in,
                              void* d_out, int out_size, void* d_ws, size_t ws_size,
                              hipStream_t stream) {
  const float* x    = (const float*)d_in[0];
  const int*   esrc = (const int*)d_in[1];
  const int*   edst = (const int*)d_in[2];
  const float* ew   = (const float*)d_in[3];
  const float* W1   = (const float*)d_in[4];
  const float* b1   = (const float*)d_in[5];
  const float* W2   = (const float*)d_in[6];
  const float* b2   = (const float*)d_in[7];
  float* out = (float*)d_out;

  const int N = in_sizes[0] / IN_DIM;
  const int E = in_sizes[1];
  const int NB = (N + BNODES - 1) >> SHIFT;         // 391 @ N=100k
  const int PBLK = (E + CH - 1) / CH;               // 196 @ E=1.6M

  char* p = (char*)d_ws;
  auto alloc = [&](size_t bytes) {
    char* r = p;
    p += (bytes + 15) & ~(size_t)15;
    return r;
  };
  unsigned short* h1 = (unsigned short*)alloc((size_t)N * HID * sizeof(unsigned short));
  float* h3          = (float*)alloc((size_t)N * sizeof(float));
  int*   bucket_size = (int*)alloc((size_t)NB * sizeof(int));
  int*   bucket_offs = (int*)alloc((size_t)(NB + 1) * sizeof(int));
  int*   noffs       = (int*)alloc((size_t)(N + 1) * sizeof(int));
  int*   blockRel    = (int*)alloc((size_t)PBLK * NB * sizeof(int));
  int2*  bpart       = (int2*)alloc((size_t)E * sizeof(int2));
  int2*  csr         = (int2*)alloc((size_t)E * sizeof(int2));

  hipMemsetAsync(bucket_size, 0, (size_t)NB * sizeof(int), stream);

  gemm1_kernel<<<(N + 63) / 64, 256, 0, stream>>>(x, W1, b1, h1, N);

  bucket_count_kernel<<<PBLK, 256, 0, stream>>>(edst, bucket_size, blockRel, NB, E);
  bucket_scan_kernel<<<1, 1024, 0, stream>>>(bucket_size, bucket_offs, NB);
  bucket_place_kernel<<<PBLK, 256, 0, stream>>>(esrc, edst, ew, bucket_offs,
                                                blockRel, bpart, NB, E);
  csr_place_kernel<<<NB, 256, 0, stream>>>(bpart, bucket_offs, csr, noffs, N, NB, E);

  spmm1_fused_kernel<<<(unsigned)(((long)N * 64 + 255) / 256), 256, 0, stream>>>(
      noffs, csr, h1, W2, b2, h3, N);

  spmm2_gather_kernel<<<(N + 255) / 256, 256, 0, stream>>>(noffs, csr, h3, out, N);
}